// Round 1
// baseline (4850.726 us; speedup 1.0000x reference)
//
#include <hip/hip_runtime.h>
#include <hip/hip_bf16.h>

#define C_ 128
#define EPS 1e-5f

static __device__ __forceinline__ float wave_reduce(float v) {
    #pragma unroll
    for (int off = 32; off; off >>= 1) v += __shfl_xor(v, off);
    return v;
}

// ---------------- generic fp32 tiled GEMM: C = act(A[M,K] @ B[K,N] + bias) ----------------
#define BM 64
#define BN 64
#define BK 16
template<int ACT>  // 0=none, 1=relu
__global__ __launch_bounds__(256) void gemm_bias(const float* __restrict__ A,
                                                 const float* __restrict__ B,
                                                 const float* __restrict__ bias,
                                                 float* __restrict__ Cmat,
                                                 int M, int N, int K) {
    __shared__ float As[BK][BM + 1];
    __shared__ float Bs[BK][BN + 1];
    int tid = threadIdx.x;
    int row0 = blockIdx.y * BM;
    int col0 = blockIdx.x * BN;
    int tx = tid & 15, ty = tid >> 4;
    float acc[4][4] = {};
    for (int k0 = 0; k0 < K; k0 += BK) {
        for (int i = tid; i < BM * BK; i += 256) {
            int m = i >> 4, kk = i & 15;
            int r = row0 + m, k = k0 + kk;
            As[kk][m] = (r < M && k < K) ? A[(size_t)r * K + k] : 0.f;
        }
        for (int i = tid; i < BK * BN; i += 256) {
            int kk = i >> 6, n = i & 63;
            int k = k0 + kk;
            Bs[kk][n] = (k < K) ? B[(size_t)k * N + col0 + n] : 0.f;
        }
        __syncthreads();
        #pragma unroll
        for (int kk = 0; kk < BK; ++kk) {
            float a[4], b[4];
            #pragma unroll
            for (int j = 0; j < 4; ++j) a[j] = As[kk][ty * 4 + j];
            #pragma unroll
            for (int j = 0; j < 4; ++j) b[j] = Bs[kk][tx * 4 + j];
            #pragma unroll
            for (int ii = 0; ii < 4; ++ii)
                #pragma unroll
                for (int jj = 0; jj < 4; ++jj)
                    acc[ii][jj] += a[ii] * b[jj];
        }
        __syncthreads();
    }
    #pragma unroll
    for (int ii = 0; ii < 4; ++ii) {
        int r = row0 + ty * 4 + ii;
        if (r >= M) continue;
        #pragma unroll
        for (int jj = 0; jj < 4; ++jj) {
            int c = col0 + tx * 4 + jj;
            float v = acc[ii][jj];
            if (bias) v += bias[c];
            if (ACT == 1) v = fmaxf(v, 0.f);
            Cmat[(size_t)r * N + c] = v;
        }
    }
}

// ---------------- gate GEMM: h_new = beta*h + (1-beta)*relu(agg), beta=relu([h,hh,h-hh]@gw+gb) ----
__global__ __launch_bounds__(256) void gate_gemm(const float* __restrict__ h,
                                                 const float* __restrict__ agg,
                                                 const float* __restrict__ gw,
                                                 const float* __restrict__ gb,
                                                 float* __restrict__ hnew, int M) {
    __shared__ float As[BK][BM + 1];
    __shared__ float Bs[BK][BN + 1];
    int tid = threadIdx.x;
    int row0 = blockIdx.y * BM;
    int col0 = blockIdx.x * BN;
    int tx = tid & 15, ty = tid >> 4;
    float acc[4][4] = {};
    for (int k0 = 0; k0 < 384; k0 += BK) {
        for (int i = tid; i < BM * BK; i += 256) {
            int m = i >> 4, kk = i & 15;
            int r = row0 + m, k = k0 + kk;
            float v = 0.f;
            if (r < M) {
                if (k < 128) v = h[(size_t)r * 128 + k];
                else if (k < 256) v = fmaxf(agg[(size_t)r * 128 + (k - 128)], 0.f);
                else {
                    float hv = h[(size_t)r * 128 + (k - 256)];
                    float hhv = fmaxf(agg[(size_t)r * 128 + (k - 256)], 0.f);
                    v = hv - hhv;
                }
            }
            As[kk][m] = v;
        }
        for (int i = tid; i < BK * BN; i += 256) {
            int kk = i >> 6, n = i & 63;
            Bs[kk][n] = gw[(size_t)(k0 + kk) * 128 + col0 + n];
        }
        __syncthreads();
        #pragma unroll
        for (int kk = 0; kk < BK; ++kk) {
            float a[4], b[4];
            #pragma unroll
            for (int j = 0; j < 4; ++j) a[j] = As[kk][ty * 4 + j];
            #pragma unroll
            for (int j = 0; j < 4; ++j) b[j] = Bs[kk][tx * 4 + j];
            #pragma unroll
            for (int ii = 0; ii < 4; ++ii)
                #pragma unroll
                for (int jj = 0; jj < 4; ++jj)
                    acc[ii][jj] += a[ii] * b[jj];
        }
        __syncthreads();
    }
    #pragma unroll
    for (int ii = 0; ii < 4; ++ii) {
        int r = row0 + ty * 4 + ii;
        if (r >= M) continue;
        #pragma unroll
        for (int jj = 0; jj < 4; ++jj) {
            int c = col0 + tx * 4 + jj;
            float beta = fmaxf(acc[ii][jj] + gb[c], 0.f);
            float hv = h[(size_t)r * 128 + c];
            float hhv = fmaxf(agg[(size_t)r * 128 + c], 0.f);
            hnew[(size_t)r * 128 + c] = beta * hv + (1.f - beta) * hhv;
        }
    }
}

// ---------------- batch norm ----------------
__global__ void bn_stats(const float* __restrict__ z, float* __restrict__ gsum,
                         float* __restrict__ gsq, int M) {
    int c = threadIdx.x & 127;
    int rr = threadIdx.x >> 7;
    float s = 0.f, q = 0.f;
    for (int r = blockIdx.x * 2 + rr; r < M; r += gridDim.x * 2) {
        float v = z[(size_t)r * 128 + c];
        s += v; q += v * v;
    }
    __shared__ float ls[256], lq[256];
    ls[threadIdx.x] = s; lq[threadIdx.x] = q;
    __syncthreads();
    if (threadIdx.x < 128) {
        atomicAdd(&gsum[c], ls[threadIdx.x] + ls[threadIdx.x + 128]);
        atomicAdd(&gsq[c], lq[threadIdx.x] + lq[threadIdx.x + 128]);
    }
}

__global__ void bn_apply(float* __restrict__ z, const float* __restrict__ gsum,
                         const float* __restrict__ gsq, const float* __restrict__ g,
                         const float* __restrict__ b, int M) {
    size_t total = (size_t)M * 128;
    for (size_t idx = (size_t)blockIdx.x * 256 + threadIdx.x; idx < total;
         idx += (size_t)gridDim.x * 256) {
        int c = idx & 127;
        float mu = gsum[c] / (float)M;
        float var = gsq[c] / (float)M - mu * mu;
        float rs = rsqrtf(var + EPS);
        float v = (z[idx] - mu) * rs * g[c] + b[c];
        z[idx] = fmaxf(v, 0.f);
    }
}

// ---------------- edge kernels ----------------
// score[e*8+s] = dot(xp[dst], yps[src]) for fixed s
__global__ __launch_bounds__(256) void edge_score(const float* __restrict__ xp,
                                                  const float* __restrict__ yps,
                                                  const int* __restrict__ ei,
                                                  float* __restrict__ score, int E, int s) {
    int e = blockIdx.x * 4 + (threadIdx.x >> 6);
    if (e >= E) return;
    int l = threadIdx.x & 63;
    int src = ei[e], dst = ei[E + e];
    const float* xi = xp + (size_t)dst * 128;
    const float* yj = yps + (size_t)src * 128;
    float p = xi[l] * yj[l] + xi[l + 64] * yj[l + 64];
    p = wave_reduce(p);
    if (l == 0) score[(size_t)e * 8 + s] = p;
}

__global__ __launch_bounds__(256) void edge_finalize(const float* __restrict__ xp,
                                                     const float* __restrict__ ep,
                                                     const float* __restrict__ score,
                                                     const int* __restrict__ ei,
                                                     const float* __restrict__ wl,
                                                     const float* __restrict__ wlb,
                                                     float* __restrict__ agg, int E) {
    __shared__ float swl[384][9];
    __shared__ float swlb[8];
    for (int i = threadIdx.x; i < 384 * 8; i += 256) swl[i >> 3][i & 7] = wl[i];
    if (threadIdx.x < 8) swlb[threadIdx.x] = wlb[threadIdx.x];
    __syncthreads();
    int e = blockIdx.x * 4 + (threadIdx.x >> 6);
    if (e >= E) return;
    int l = threadIdx.x & 63;
    int src = ei[e], dst = ei[E + e];
    const float* xpS = xp + (size_t)src * 128;
    const float* xpD = xp + (size_t)dst * 128;
    const float* epr = ep + (size_t)e * 128;
    float xi0 = xpD[l], xi1 = xpD[l + 64];
    float xj0 = xpS[l], xj1 = xpS[l + 64];
    float ep0 = epr[l], ep1 = epr[l + 64];
    float bp[8];
    #pragma unroll
    for (int s = 0; s < 8; ++s) {
        bp[s] = xi0 * swl[l][s] + xi1 * swl[l + 64][s]
              + ep0 * swl[128 + l][s] + ep1 * swl[128 + l + 64][s]
              + xj0 * swl[256 + l][s] + xj1 * swl[256 + l + 64][s];
    }
    #pragma unroll
    for (int s = 0; s < 8; ++s) bp[s] = wave_reduce(bp[s]);
    float al[8];
    #pragma unroll
    for (int s = 0; s < 8; ++s)
        al[s] = tanhf(score[(size_t)e * 8 + s] + bp[s] + swlb[s]);
    int g0 = l >> 4;  // 0..3
    float a0 = g0 == 0 ? al[0] : g0 == 1 ? al[1] : g0 == 2 ? al[2] : al[3];
    float a1 = g0 == 0 ? al[4] : g0 == 1 ? al[5] : g0 == 2 ? al[6] : al[7];
    float m0 = fmaxf(xj0, ep0) * a0;
    float m1 = fmaxf(xj1, ep1) * a1;
    atomicAdd(&agg[(size_t)dst * 128 + l], m0);
    atomicAdd(&agg[(size_t)dst * 128 + l + 64], m1);
}

// ---------------- small prep kernels ----------------
__global__ void transpose_wb(const float* __restrict__ wb, float* __restrict__ wbT) {
    int idx = blockIdx.x * 256 + threadIdx.x;
    if (idx >= 3 * 8 * 128 * 128) return;
    int ls = idx >> 14;
    int d = (idx >> 7) & 127;
    int c = idx & 127;
    wbT[idx] = wb[((size_t)ls << 14) + (c << 7) + d];
}

__global__ void build_wm(const float* __restrict__ wsrc, float* __restrict__ wm) {
    int idx = blockIdx.x * 256 + threadIdx.x;
    if (idx >= 128 * 128) return;
    int d = idx >> 7, c = idx & 127;
    float s = 0.f;
    #pragma unroll
    for (int h = 0; h < 8; ++h) s += wsrc[(size_t)d * 1024 + h * 128 + c];
    wm[idx] = s * 0.125f;
}

__global__ void perm_build(const int* __restrict__ ci, int* __restrict__ perm, int NF) {
    int i = blockIdx.x * 256 + threadIdx.x;
    if (i >= NF) return;
    int c = ci[i];
    if (i == 0 || ci[i - 1] != c) perm[c] = i;
}

__global__ void seg_pool(const float* __restrict__ fx, const int* __restrict__ perm,
                         float* __restrict__ pool, int F, int NF) {
    int idx = blockIdx.x * 256 + threadIdx.x;
    if (idx >= F * 128) return;
    int f = idx >> 7, c = idx & 127;
    int s = perm[f];
    int e = (f + 1 < F) ? perm[f + 1] : NF;
    float acc = 0.f;
    for (int i = s; i < e; ++i) acc += fx[(size_t)i * 128 + c];
    pool[idx] = fmaxf(acc, 0.f);
}

// ---------------- output ----------------
__global__ __launch_bounds__(256) void out_phase1(const float* __restrict__ h,
                                                  const float* __restrict__ out_w,
                                                  const float* __restrict__ out_b,
                                                  const float* __restrict__ gat_bias,
                                                  float* __restrict__ out, int M) {
    int n = blockIdx.x * 4 + (threadIdx.x >> 6);
    if (n >= M) return;
    int l = threadIdx.x & 63;
    float p = fmaxf(h[(size_t)n * 128 + l], 0.f) * out_w[l]
            + fmaxf(h[(size_t)n * 128 + l + 64], 0.f) * out_w[l + 64];
    p += fmaxf(gat_bias[l], 0.f) * out_w[128 + l]
       + fmaxf(gat_bias[l + 64], 0.f) * out_w[128 + l + 64];
    p = wave_reduce(p);
    if (l == 0) out[n] = p + out_b[0];
}

__global__ __launch_bounds__(256) void out_phase2(const float* __restrict__ fmv,
                                                  const int* __restrict__ perm,
                                                  const float* __restrict__ out_w,
                                                  const float* __restrict__ gat_bias,
                                                  float* __restrict__ out, int F) {
    int f = blockIdx.x * 4 + (threadIdx.x >> 6);
    if (f >= F) return;
    int l = threadIdx.x & 63;
    float p = fmv[(size_t)f * 128 + l] * out_w[128 + l]
            + fmv[(size_t)f * 128 + l + 64] * out_w[128 + l + 64];
    float b = fmaxf(gat_bias[l], 0.f) * out_w[128 + l]
            + fmaxf(gat_bias[l + 64], 0.f) * out_w[128 + l + 64];
    float d = wave_reduce(p - b);
    if (l == 0) out[perm[f]] += d;
}

// ---------------- host ----------------
extern "C" void kernel_launch(void* const* d_in, const int* in_sizes, int n_in,
                              void* d_out, int out_size, void* d_ws, size_t ws_size,
                              hipStream_t stream) {
    const int N = 50000, E = 100000, NF = 20000, EF = 40000, F = 10000;

    const float* x          = (const float*)d_in[0];
    const float* edge_attr  = (const float*)d_in[1];
    const float* frag_x     = (const float*)d_in[2];
    const float* frag_ea    = (const float*)d_in[3];
    const float* la_w = (const float*)d_in[4];
    const float* la_b = (const float*)d_in[5];
    const float* lb_w = (const float*)d_in[6];
    const float* lb_b = (const float*)d_in[7];
    const float* bn1_g = (const float*)d_in[8];
    const float* bn1_b = (const float*)d_in[9];
    const float* bn2_g = (const float*)d_in[10];
    const float* bn2_b = (const float*)d_in[11];
    const float* wn = (const float*)d_in[12];
    const float* wb = (const float*)d_in[13];
    const float* wl = (const float*)d_in[14];
    const float* wlb = (const float*)d_in[15];
    const float* gate_w = (const float*)d_in[16];
    const float* gate_b = (const float*)d_in[17];
    const float* gat_wsrc = (const float*)d_in[18];
    const float* gat_bias = (const float*)d_in[22];
    const float* out_w = (const float*)d_in[23];
    const float* out_b = (const float*)d_in[24];
    const int* edge_index = (const int*)d_in[25];
    const int* frag_edge_index = (const int*)d_in[26];
    const int* cluster_index = (const int*)d_in[27];

    float* ws = (float*)d_ws;
    float* hA   = ws;               ws += (size_t)N * 128;
    float* hB   = ws;               ws += (size_t)N * 128;
    float* ea1  = ws;               ws += (size_t)E * 128;
    float* xp   = ws;               ws += (size_t)N * 128;
    float* ep   = ws;               ws += (size_t)E * 128;
    float* yps  = ws;               ws += (size_t)N * 128;
    float* score = ws;              ws += (size_t)E * 8;
    float* agg  = ws;               ws += (size_t)N * 128;
    float* wbT  = ws;               ws += 3 * 8 * 128 * 128;
    float* wm   = ws;               ws += 128 * 128;
    float* stats = ws;              ws += 256;
    float* fpool = ws;              ws += (size_t)F * 128;
    float* fmv  = ws;               ws += (size_t)F * 128;
    int* perm = (int*)ws;

    auto cdiv = [](int a, int b) { return (a + b - 1) / b; };

    auto run_layer = [&](float* h_in, float* h_out, const float* ea_buf,
                         const int* ei, int Mn, int Me, int layer) {
        const float* wn_l  = wn + (size_t)layer * 128 * 128;
        const float* wl_l  = wl + (size_t)layer * 384 * 8;
        const float* wlb_l = wlb + (size_t)layer * 8;
        gemm_bias<0><<<dim3(2, cdiv(Mn, 64)), 256, 0, stream>>>(h_in, wn_l, nullptr, xp, Mn, 128, 128);
        gemm_bias<0><<<dim3(2, cdiv(Me, 64)), 256, 0, stream>>>(ea_buf, wn_l, nullptr, ep, Me, 128, 128);
        for (int s = 0; s < 8; ++s) {
            const float* wbT_ls = wbT + (size_t)(layer * 8 + s) * 128 * 128;
            gemm_bias<0><<<dim3(2, cdiv(Mn, 64)), 256, 0, stream>>>(xp, wbT_ls, nullptr, yps, Mn, 128, 128);
            edge_score<<<cdiv(Me, 4), 256, 0, stream>>>(xp, yps, ei, score, Me, s);
        }
        hipMemsetAsync(agg, 0, (size_t)Mn * 128 * 4, stream);
        edge_finalize<<<cdiv(Me, 4), 256, 0, stream>>>(xp, ep, score, ei, wl_l, wlb_l, agg, Me);
        gate_gemm<<<dim3(2, cdiv(Mn, 64)), 256, 0, stream>>>(h_in, agg, gate_w, gate_b, h_out, Mn);
    };

    // ---- prep ----
    transpose_wb<<<cdiv(3 * 8 * 128 * 128, 256), 256, 0, stream>>>(wb, wbT);
    build_wm<<<cdiv(128 * 128, 256), 256, 0, stream>>>(gat_wsrc, wm);

    // ---- atom path ----
    gemm_bias<0><<<dim3(2, cdiv(N, 64)), 256, 0, stream>>>(x, la_w, la_b, hA, N, 128, 128);
    hipMemsetAsync(stats, 0, 1024, stream);
    bn_stats<<<256, 256, 0, stream>>>(hA, stats, stats + 128, N);
    bn_apply<<<2048, 256, 0, stream>>>(hA, stats, stats + 128, bn1_g, bn1_b, N);

    gemm_bias<0><<<dim3(2, cdiv(E, 64)), 256, 0, stream>>>(edge_attr, lb_w, lb_b, ea1, E, 128, 16);
    hipMemsetAsync(stats, 0, 1024, stream);
    bn_stats<<<256, 256, 0, stream>>>(ea1, stats, stats + 128, E);
    bn_apply<<<2048, 256, 0, stream>>>(ea1, stats, stats + 128, bn2_g, bn2_b, E);

    float* cur = hA; float* nxt = hB;
    for (int l = 0; l < 3; ++l) {
        run_layer(cur, nxt, ea1, edge_index, N, E, l);
        float* t = cur; cur = nxt; nxt = t;
    }
    out_phase1<<<cdiv(N, 4), 256, 0, stream>>>(cur, out_w, out_b, gat_bias, (float*)d_out, N);

    // ---- fragment path (reuses atom buffers) ----
    gemm_bias<1><<<dim3(2, cdiv(NF, 64)), 256, 0, stream>>>(frag_x, la_w, la_b, hA, NF, 128, 128);
    gemm_bias<0><<<dim3(2, cdiv(EF, 64)), 256, 0, stream>>>(frag_ea, lb_w, lb_b, ea1, EF, 128, 16);
    hipMemsetAsync(stats, 0, 1024, stream);
    bn_stats<<<256, 256, 0, stream>>>(ea1, stats, stats + 128, EF);
    bn_apply<<<2048, 256, 0, stream>>>(ea1, stats, stats + 128, bn2_g, bn2_b, EF);

    cur = hA; nxt = hB;
    for (int l = 0; l < 3; ++l) {
        run_layer(cur, nxt, ea1, frag_edge_index, NF, EF, l);
        float* t = cur; cur = nxt; nxt = t;
    }

    perm_build<<<cdiv(NF, 256), 256, 0, stream>>>(cluster_index, perm, NF);
    seg_pool<<<cdiv(F * 128, 256), 256, 0, stream>>>(cur, perm, fpool, F, NF);
    gemm_bias<1><<<dim3(2, cdiv(F, 64)), 256, 0, stream>>>(fpool, wm, gat_bias, fmv, F, 128, 128);
    out_phase2<<<cdiv(F, 4), 256, 0, stream>>>(fmv, perm, out_w, gat_bias, (float*)d_out, F);
}

// Round 3
// 1771.231 us; speedup vs baseline: 2.7386x; 2.7386x over previous
//
#include <hip/hip_runtime.h>
#include <hip/hip_bf16.h>

#define EPS 1e-5f

typedef short bf16x8 __attribute__((ext_vector_type(8)));
typedef short short4v __attribute__((ext_vector_type(4)));
typedef float f32x4 __attribute__((ext_vector_type(4)));

static __device__ __forceinline__ short f2bf(float x) {
    __hip_bfloat16 h = __float2bfloat16(x);
    return *reinterpret_cast<short*>(&h);
}
static __device__ __forceinline__ float bf2f(short x) {
    __hip_bfloat16 h;
    *reinterpret_cast<short*>(&h) = x;
    return __bfloat162float(h);
}

static __device__ __forceinline__ float wave_reduce(float v) {
    #pragma unroll
    for (int off = 32; off; off >>= 1) v += __shfl_xor(v, off);
    return v;
}

// ========== split-bf16 MFMA GEMM: C = act(A[M,K](f32) @ BT[N,K]^T + bias) ==========
// SPLIT=3: A hi/lo, B hi/lo (3 MFMA terms, ~fp32 accuracy)
// SPLIT=2: A hi/lo, B hi only (2 MFMA terms)
template<int SPLIT, int ACT, int OUTBF>
__global__ __launch_bounds__(256) void gemm_split(const float* __restrict__ A,
                                                  const short* __restrict__ BTh,
                                                  const short* __restrict__ BTl,
                                                  const float* __restrict__ bias,
                                                  void* __restrict__ Cout,
                                                  int M, int N, int K) {
    __shared__ short Ah[128][40];
    __shared__ short Al[128][40];
    __shared__ short Bh[128][40];
    __shared__ short Bl[128][40];
    const int tid = threadIdx.x;
    const int row0 = blockIdx.y * 128, col0 = blockIdx.x * 128;
    const int lane = tid & 63, w = tid >> 6;
    const int wr = w >> 1, wc = w & 1;
    const int lr = lane & 15, lg = lane >> 4;
    f32x4 acc[4][4] = {};

    for (int k0 = 0; k0 < K; k0 += 32) {
        // stage A (f32 -> hi/lo bf16)
        #pragma unroll
        for (int i = 0; i < 4; ++i) {
            int idx = i * 256 + tid;
            int r = idx >> 3, q = idx & 7;
            int gr = row0 + r, gk = k0 + q * 4;
            f32x4 v;
            if (gr < M && gk + 3 < K) {
                v = *reinterpret_cast<const f32x4*>(&A[(size_t)gr * K + gk]);
            } else {
                #pragma unroll
                for (int j = 0; j < 4; ++j)
                    v[j] = (gr < M && gk + j < K) ? A[(size_t)gr * K + gk + j] : 0.f;
            }
            short4v h, l;
            #pragma unroll
            for (int j = 0; j < 4; ++j) {
                h[j] = f2bf(v[j]);
                l[j] = f2bf(v[j] - bf2f(h[j]));
            }
            *reinterpret_cast<short4v*>(&Ah[r][q * 4]) = h;
            *reinterpret_cast<short4v*>(&Al[r][q * 4]) = l;
        }
        // stage B (pre-split bf16)
        #pragma unroll
        for (int i = 0; i < 4; ++i) {
            int idx = i * 256 + tid;
            int r = idx >> 3, q = idx & 7;
            int gc = col0 + r, gk = k0 + q * 4;
            short4v u, ul;
            if (gk + 3 < K) {
                u = *reinterpret_cast<const short4v*>(&BTh[(size_t)gc * K + gk]);
                if (SPLIT == 3) ul = *reinterpret_cast<const short4v*>(&BTl[(size_t)gc * K + gk]);
            } else {
                #pragma unroll
                for (int j = 0; j < 4; ++j) {
                    u[j] = (gk + j < K) ? BTh[(size_t)gc * K + gk + j] : (short)0;
                    if (SPLIT == 3) ul[j] = (gk + j < K) ? BTl[(size_t)gc * K + gk + j] : (short)0;
                }
            }
            *reinterpret_cast<short4v*>(&Bh[r][q * 4]) = u;
            if (SPLIT == 3) *reinterpret_cast<short4v*>(&Bl[r][q * 4]) = ul;
        }
        __syncthreads();
        bf16x8 afh[4], afl[4], bfh[4];
        #pragma unroll
        for (int mi = 0; mi < 4; ++mi) {
            afh[mi] = *reinterpret_cast<const bf16x8*>(&Ah[wr * 64 + mi * 16 + lr][lg * 8]);
            afl[mi] = *reinterpret_cast<const bf16x8*>(&Al[wr * 64 + mi * 16 + lr][lg * 8]);
        }
        #pragma unroll
        for (int ni = 0; ni < 4; ++ni)
            bfh[ni] = *reinterpret_cast<const bf16x8*>(&Bh[wc * 64 + ni * 16 + lr][lg * 8]);
        #pragma unroll
        for (int mi = 0; mi < 4; ++mi)
            #pragma unroll
            for (int ni = 0; ni < 4; ++ni) {
                acc[mi][ni] = __builtin_amdgcn_mfma_f32_16x16x32_bf16(afh[mi], bfh[ni], acc[mi][ni], 0, 0, 0);
                acc[mi][ni] = __builtin_amdgcn_mfma_f32_16x16x32_bf16(afl[mi], bfh[ni], acc[mi][ni], 0, 0, 0);
            }
        if (SPLIT == 3) {
            bf16x8 bfl[4];
            #pragma unroll
            for (int ni = 0; ni < 4; ++ni)
                bfl[ni] = *reinterpret_cast<const bf16x8*>(&Bl[wc * 64 + ni * 16 + lr][lg * 8]);
            #pragma unroll
            for (int mi = 0; mi < 4; ++mi)
                #pragma unroll
                for (int ni = 0; ni < 4; ++ni)
                    acc[mi][ni] = __builtin_amdgcn_mfma_f32_16x16x32_bf16(afh[mi], bfl[ni], acc[mi][ni], 0, 0, 0);
        }
        __syncthreads();
    }

    #pragma unroll
    for (int mi = 0; mi < 4; ++mi) {
        #pragma unroll
        for (int ni = 0; ni < 4; ++ni) {
            int col = col0 + wc * 64 + ni * 16 + lr;
            float bv = bias ? bias[col] : 0.f;
            #pragma unroll
            for (int r = 0; r < 4; ++r) {
                int row = row0 + wr * 64 + mi * 16 + lg * 4 + r;
                if (row >= M) continue;
                float v = acc[mi][ni][r] + bv;
                if (ACT) v = fmaxf(v, 0.f);
                if (OUTBF) ((short*)Cout)[(size_t)row * N + col] = f2bf(v);
                else       ((float*)Cout)[(size_t)row * N + col] = v;
            }
        }
    }
}

// ========== plain bf16 GEMM (tolerant path: ep projection) ==========
template<int ACT, int OUTBF>
__global__ __launch_bounds__(256) void gemm_bf16(const short* __restrict__ A,
                                                 const short* __restrict__ BT,
                                                 const float* __restrict__ bias,
                                                 void* __restrict__ Cout,
                                                 int M, int N, int K) {
    __shared__ short As[128][40];
    __shared__ short Bs[128][40];
    const int tid = threadIdx.x;
    const int row0 = blockIdx.y * 128, col0 = blockIdx.x * 128;
    const int lane = tid & 63, w = tid >> 6;
    const int wr = w >> 1, wc = w & 1;
    const int lr = lane & 15, lg = lane >> 4;
    f32x4 acc[4][4] = {};

    for (int k0 = 0; k0 < K; k0 += 32) {
        #pragma unroll
        for (int i = 0; i < 4; ++i) {
            int idx = i * 256 + tid;
            int r = idx >> 3, q = idx & 7;
            int gk = k0 + q * 4;
            int gr = row0 + r;
            short4v v;
            if (gr < M && gk + 3 < K) {
                v = *reinterpret_cast<const short4v*>(&A[(size_t)gr * K + gk]);
            } else {
                #pragma unroll
                for (int j = 0; j < 4; ++j)
                    v[j] = (gr < M && gk + j < K) ? A[(size_t)gr * K + gk + j] : (short)0;
            }
            *reinterpret_cast<short4v*>(&As[r][q * 4]) = v;
            int gc = col0 + r;
            short4v u;
            if (gc < N && gk + 3 < K) {
                u = *reinterpret_cast<const short4v*>(&BT[(size_t)gc * K + gk]);
            } else {
                #pragma unroll
                for (int j = 0; j < 4; ++j)
                    u[j] = (gc < N && gk + j < K) ? BT[(size_t)gc * K + gk + j] : (short)0;
            }
            *reinterpret_cast<short4v*>(&Bs[r][q * 4]) = u;
        }
        __syncthreads();
        bf16x8 af[4], bfr[4];
        #pragma unroll
        for (int mi = 0; mi < 4; ++mi)
            af[mi] = *reinterpret_cast<const bf16x8*>(&As[wr * 64 + mi * 16 + lr][lg * 8]);
        #pragma unroll
        for (int ni = 0; ni < 4; ++ni)
            bfr[ni] = *reinterpret_cast<const bf16x8*>(&Bs[wc * 64 + ni * 16 + lr][lg * 8]);
        #pragma unroll
        for (int mi = 0; mi < 4; ++mi)
            #pragma unroll
            for (int ni = 0; ni < 4; ++ni)
                acc[mi][ni] = __builtin_amdgcn_mfma_f32_16x16x32_bf16(af[mi], bfr[ni], acc[mi][ni], 0, 0, 0);
        __syncthreads();
    }

    #pragma unroll
    for (int mi = 0; mi < 4; ++mi) {
        #pragma unroll
        for (int ni = 0; ni < 4; ++ni) {
            int col = col0 + wc * 64 + ni * 16 + lr;
            float bv = bias ? bias[col] : 0.f;
            #pragma unroll
            for (int r = 0; r < 4; ++r) {
                int row = row0 + wr * 64 + mi * 16 + lg * 4 + r;
                if (row >= M) continue;
                float v = acc[mi][ni][r] + bv;
                if (ACT) v = fmaxf(v, 0.f);
                if (OUTBF) ((short*)Cout)[(size_t)row * N + col] = f2bf(v);
                else       ((float*)Cout)[(size_t)row * N + col] = v;
            }
        }
    }
}

// ========== gate GEMM (split-3): beta=relu([h,relu(agg),h-relu(agg)]@gw+gb) ==========
// writes h in place: hnew = beta*h + (1-beta)*relu(agg). Each block owns its rows.
__global__ __launch_bounds__(256) void gate_gemm_split(float* __restrict__ h,
                                                       const float* __restrict__ aggv,
                                                       const short* __restrict__ BTh,  // [128][384]
                                                       const short* __restrict__ BTl,
                                                       const float* __restrict__ gb,
                                                       int M) {
    __shared__ short Ah[128][40];
    __shared__ short Al[128][40];
    __shared__ short Bh[128][40];
    __shared__ short Bl[128][40];
    const int tid = threadIdx.x;
    const int row0 = blockIdx.y * 128;
    const int lane = tid & 63, w = tid >> 6;
    const int wr = w >> 1, wc = w & 1;
    const int lr = lane & 15, lg = lane >> 4;
    f32x4 acc[4][4] = {};

    for (int k0 = 0; k0 < 384; k0 += 32) {
        int sec = k0 >> 7;
        #pragma unroll
        for (int i = 0; i < 4; ++i) {
            int idx = i * 256 + tid;
            int r = idx >> 3, q = idx & 7;
            int gr = row0 + r;
            int ks = (k0 & 127) + q * 4;
            f32x4 v;
            if (gr < M) {
                if (sec == 0) {
                    v = *reinterpret_cast<const f32x4*>(&h[(size_t)gr * 128 + ks]);
                } else if (sec == 1) {
                    f32x4 a = *reinterpret_cast<const f32x4*>(&aggv[(size_t)gr * 128 + ks]);
                    #pragma unroll
                    for (int j = 0; j < 4; ++j) v[j] = fmaxf(a[j], 0.f);
                } else {
                    f32x4 hv = *reinterpret_cast<const f32x4*>(&h[(size_t)gr * 128 + ks]);
                    f32x4 a = *reinterpret_cast<const f32x4*>(&aggv[(size_t)gr * 128 + ks]);
                    #pragma unroll
                    for (int j = 0; j < 4; ++j) v[j] = hv[j] - fmaxf(a[j], 0.f);
                }
            } else {
                #pragma unroll
                for (int j = 0; j < 4; ++j) v[j] = 0.f;
            }
            short4v hh, ll;
            #pragma unroll
            for (int j = 0; j < 4; ++j) {
                hh[j] = f2bf(v[j]);
                ll[j] = f2bf(v[j] - bf2f(hh[j]));
            }
            *reinterpret_cast<short4v*>(&Ah[r][q * 4]) = hh;
            *reinterpret_cast<short4v*>(&Al[r][q * 4]) = ll;
        }
        #pragma unroll
        for (int i = 0; i < 4; ++i) {
            int idx = i * 256 + tid;
            int r = idx >> 3, q = idx & 7;
            short4v u  = *reinterpret_cast<const short4v*>(&BTh[(size_t)r * 384 + k0 + q * 4]);
            short4v ul = *reinterpret_cast<const short4v*>(&BTl[(size_t)r * 384 + k0 + q * 4]);
            *reinterpret_cast<short4v*>(&Bh[r][q * 4]) = u;
            *reinterpret_cast<short4v*>(&Bl[r][q * 4]) = ul;
        }
        __syncthreads();
        bf16x8 afh[4], afl[4], bfh[4], bfl[4];
        #pragma unroll
        for (int mi = 0; mi < 4; ++mi) {
            afh[mi] = *reinterpret_cast<const bf16x8*>(&Ah[wr * 64 + mi * 16 + lr][lg * 8]);
            afl[mi] = *reinterpret_cast<const bf16x8*>(&Al[wr * 64 + mi * 16 + lr][lg * 8]);
        }
        #pragma unroll
        for (int ni = 0; ni < 4; ++ni) {
            bfh[ni] = *reinterpret_cast<const bf16x8*>(&Bh[wc * 64 + ni * 16 + lr][lg * 8]);
            bfl[ni] = *reinterpret_cast<const bf16x8*>(&Bl[wc * 64 + ni * 16 + lr][lg * 8]);
        }
        #pragma unroll
        for (int mi = 0; mi < 4; ++mi)
            #pragma unroll
            for (int ni = 0; ni < 4; ++ni) {
                acc[mi][ni] = __builtin_amdgcn_mfma_f32_16x16x32_bf16(afh[mi], bfh[ni], acc[mi][ni], 0, 0, 0);
                acc[mi][ni] = __builtin_amdgcn_mfma_f32_16x16x32_bf16(afl[mi], bfh[ni], acc[mi][ni], 0, 0, 0);
                acc[mi][ni] = __builtin_amdgcn_mfma_f32_16x16x32_bf16(afh[mi], bfl[ni], acc[mi][ni], 0, 0, 0);
            }
        __syncthreads();
    }

    #pragma unroll
    for (int mi = 0; mi < 4; ++mi) {
        #pragma unroll
        for (int ni = 0; ni < 4; ++ni) {
            int col = wc * 64 + ni * 16 + lr;
            float gbv = gb[col];
            #pragma unroll
            for (int r = 0; r < 4; ++r) {
                int row = row0 + wr * 64 + mi * 16 + lg * 4 + r;
                if (row >= M) continue;
                float beta = fmaxf(acc[mi][ni][r] + gbv, 0.f);
                float hv = h[(size_t)row * 128 + col];
                float hh = fmaxf(aggv[(size_t)row * 128 + col], 0.f);
                h[(size_t)row * 128 + col] = beta * hv + (1.f - beta) * hh;
            }
        }
    }
}

// ========== fused edge kernel ==========
__global__ __launch_bounds__(256) void edge_fused(const float* __restrict__ xp,
                                                  const short* __restrict__ ep,
                                                  const short* __restrict__ Y,
                                                  const int* __restrict__ ei,
                                                  const float* __restrict__ wl,
                                                  const float* __restrict__ wlb,
                                                  float* __restrict__ agg, int E) {
    __shared__ float swl[384][9];
    __shared__ float swlb[8];
    for (int i = threadIdx.x; i < 384 * 8; i += 256) swl[i >> 3][i & 7] = wl[i];
    if (threadIdx.x < 8) swlb[threadIdx.x] = wlb[threadIdx.x];
    __syncthreads();
    int e = blockIdx.x * 4 + (threadIdx.x >> 6);
    if (e >= E) return;
    int l = threadIdx.x & 63;
    int src = ei[e], dst = ei[E + e];
    const float* xS = xp + (size_t)src * 128;
    const float* xD = xp + (size_t)dst * 128;
    const short* er = ep + (size_t)e * 128;
    const short* y  = Y + (size_t)src * 1024;
    float xi0 = xD[l], xi1 = xD[l + 64];
    float xj0 = xS[l], xj1 = xS[l + 64];
    float e0 = bf2f(er[l]), e1 = bf2f(er[l + 64]);
    float t[8];
    #pragma unroll
    for (int s = 0; s < 8; ++s) {
        float p = xi0 * (bf2f(y[s * 128 + l]) + swl[l][s])
                + xi1 * (bf2f(y[s * 128 + l + 64]) + swl[l + 64][s])
                + e0 * swl[128 + l][s] + e1 * swl[128 + l + 64][s]
                + xj0 * swl[256 + l][s] + xj1 * swl[256 + l + 64][s];
        t[s] = wave_reduce(p);
    }
    int g0 = l >> 4;
    float tg0 = (g0 == 0 ? t[0] : g0 == 1 ? t[1] : g0 == 2 ? t[2] : t[3]) + swlb[g0];
    float tg1 = (g0 == 0 ? t[4] : g0 == 1 ? t[5] : g0 == 2 ? t[6] : t[7]) + swlb[g0 + 4];
    float a0 = tanhf(tg0), a1 = tanhf(tg1);
    atomicAdd(&agg[(size_t)dst * 128 + l],      fmaxf(xj0, e0) * a0);
    atomicAdd(&agg[(size_t)dst * 128 + l + 64], fmaxf(xj1, e1) * a1);
}

// ========== batch norm (fp32) ==========
__global__ void bn_stats(const float* __restrict__ z, float* __restrict__ gsum,
                         float* __restrict__ gsq, int M) {
    int c = threadIdx.x & 127;
    int rr = threadIdx.x >> 7;
    float s = 0.f, q = 0.f;
    for (int r = blockIdx.x * 2 + rr; r < M; r += gridDim.x * 2) {
        float v = z[(size_t)r * 128 + c];
        s += v; q += v * v;
    }
    __shared__ float ls[256], lq[256];
    ls[threadIdx.x] = s; lq[threadIdx.x] = q;
    __syncthreads();
    if (threadIdx.x < 128) {
        atomicAdd(&gsum[c], ls[threadIdx.x] + ls[threadIdx.x + 128]);
        atomicAdd(&gsq[c],  lq[threadIdx.x] + lq[threadIdx.x + 128]);
    }
}

__global__ void bn_apply(float* __restrict__ z, const float* __restrict__ gsum,
                         const float* __restrict__ gsq, const float* __restrict__ g,
                         const float* __restrict__ b, int M) {
    size_t total = (size_t)M * 128;
    for (size_t idx = (size_t)blockIdx.x * 256 + threadIdx.x; idx < total;
         idx += (size_t)gridDim.x * 256) {
        int c = idx & 127;
        float mu = gsum[c] / (float)M;
        float var = gsq[c] / (float)M - mu * mu;
        float rs = rsqrtf(var + EPS);
        float v = (z[idx] - mu) * rs * g[c] + b[c];
        z[idx] = fmaxf(v, 0.f);
    }
}

// bf16 variants (for ea1)
__global__ void bn_stats_bf(const short* __restrict__ z, float* __restrict__ gsum,
                            float* __restrict__ gsq, int M) {
    int c = threadIdx.x & 127;
    int rr = threadIdx.x >> 7;
    float s = 0.f, q = 0.f;
    for (int r = blockIdx.x * 2 + rr; r < M; r += gridDim.x * 2) {
        float v = bf2f(z[(size_t)r * 128 + c]);
        s += v; q += v * v;
    }
    __shared__ float ls[256], lq[256];
    ls[threadIdx.x] = s; lq[threadIdx.x] = q;
    __syncthreads();
    if (threadIdx.x < 128) {
        atomicAdd(&gsum[c], ls[threadIdx.x] + ls[threadIdx.x + 128]);
        atomicAdd(&gsq[c],  lq[threadIdx.x] + lq[threadIdx.x + 128]);
    }
}

__global__ void bn_apply_bf(short* __restrict__ z, const float* __restrict__ gsum,
                            const float* __restrict__ gsq, const float* __restrict__ g,
                            const float* __restrict__ b, int M) {
    size_t total = (size_t)M * 128;
    for (size_t idx = (size_t)blockIdx.x * 256 + threadIdx.x; idx < total;
         idx += (size_t)gridDim.x * 256) {
        int c = idx & 127;
        float mu = gsum[c] / (float)M;
        float var = gsq[c] / (float)M - mu * mu;
        float rs = rsqrtf(var + EPS);
        float v = (bf2f(z[idx]) - mu) * rs * g[c] + b[c];
        z[idx] = f2bf(fmaxf(v, 0.f));
    }
}

// ========== prep ==========
// in[K][N] f32 -> outh[N][K], outl[N][K] (bf16 hi/lo)
__global__ void transpose_split(const float* __restrict__ in, short* __restrict__ outh,
                                short* __restrict__ outl, int K, int N) {
    int idx = blockIdx.x * 256 + threadIdx.x;
    if (idx >= K * N) return;
    int nI = idx / K, k = idx - nI * K;
    float v = in[(size_t)k * N + nI];
    short h = f2bf(v);
    outh[idx] = h;
    outl[idx] = f2bf(v - bf2f(h));
}

__global__ void cvt_f2b(const float* __restrict__ in, short* __restrict__ out, int n) {
    int i = blockIdx.x * 256 + threadIdx.x;
    if (i < n) out[i] = f2bf(in[i]);
}

__global__ void build_wm(const float* __restrict__ wsrc, float* __restrict__ wm) {
    int idx = blockIdx.x * 256 + threadIdx.x;
    if (idx >= 128 * 128) return;
    int d = idx >> 7, c = idx & 127;
    float s = 0.f;
    #pragma unroll
    for (int h = 0; h < 8; ++h) s += wsrc[(size_t)d * 1024 + h * 128 + c];
    wm[idx] = s * 0.125f;
}

__global__ void perm_build(const int* __restrict__ ci, int* __restrict__ perm, int NF) {
    int i = blockIdx.x * 256 + threadIdx.x;
    if (i >= NF) return;
    int c = ci[i];
    if (i == 0 || ci[i - 1] != c) perm[c] = i;
}

__global__ void seg_pool(const float* __restrict__ fx, const int* __restrict__ perm,
                         float* __restrict__ pool, int F, int NF) {
    int idx = blockIdx.x * 256 + threadIdx.x;
    if (idx >= F * 128) return;
    int f = idx >> 7, c = idx & 127;
    int s = perm[f];
    int e = (f + 1 < F) ? perm[f + 1] : NF;
    float acc = 0.f;
    for (int i = s; i < e; ++i) acc += fx[(size_t)i * 128 + c];
    pool[idx] = fmaxf(acc, 0.f);
}

// ========== output ==========
__global__ __launch_bounds__(256) void out_phase1(const float* __restrict__ h,
                                                  const float* __restrict__ out_w,
                                                  const float* __restrict__ out_b,
                                                  const float* __restrict__ gat_bias,
                                                  float* __restrict__ out, int M) {
    int n = blockIdx.x * 4 + (threadIdx.x >> 6);
    if (n >= M) return;
    int l = threadIdx.x & 63;
    float p = fmaxf(h[(size_t)n * 128 + l], 0.f) * out_w[l]
            + fmaxf(h[(size_t)n * 128 + l + 64], 0.f) * out_w[l + 64];
    p += fmaxf(gat_bias[l], 0.f) * out_w[128 + l]
       + fmaxf(gat_bias[l + 64], 0.f) * out_w[128 + l + 64];
    p = wave_reduce(p);
    if (l == 0) out[n] = p + out_b[0];
}

__global__ __launch_bounds__(256) void out_phase2(const float* __restrict__ fmv,
                                                  const int* __restrict__ perm,
                                                  const float* __restrict__ out_w,
                                                  const float* __restrict__ gat_bias,
                                                  float* __restrict__ out, int F) {
    int f = blockIdx.x * 4 + (threadIdx.x >> 6);
    if (f >= F) return;
    int l = threadIdx.x & 63;
    float p = fmv[(size_t)f * 128 + l] * out_w[128 + l]
            + fmv[(size_t)f * 128 + l + 64] * out_w[128 + l + 64];
    float b = fmaxf(gat_bias[l], 0.f) * out_w[128 + l]
            + fmaxf(gat_bias[l + 64], 0.f) * out_w[128 + l + 64];
    float d = wave_reduce(p - b);
    if (l == 0) out[perm[f]] += d;
}

// ========== host ==========
extern "C" void kernel_launch(void* const* d_in, const int* in_sizes, int n_in,
                              void* d_out, int out_size, void* d_ws, size_t ws_size,
                              hipStream_t stream) {
    const int N = 50000, E = 100000, NF = 20000, EF = 40000, F = 10000;

    const float* x          = (const float*)d_in[0];
    const float* edge_attr  = (const float*)d_in[1];
    const float* frag_x     = (const float*)d_in[2];
    const float* frag_ea    = (const float*)d_in[3];
    const float* la_w = (const float*)d_in[4];
    const float* la_b = (const float*)d_in[5];
    const float* lb_w = (const float*)d_in[6];
    const float* lb_b = (const float*)d_in[7];
    const float* bn1_g = (const float*)d_in[8];
    const float* bn1_b = (const float*)d_in[9];
    const float* bn2_g = (const float*)d_in[10];
    const float* bn2_b = (const float*)d_in[11];
    const float* wn = (const float*)d_in[12];
    const float* wb = (const float*)d_in[13];
    const float* wl = (const float*)d_in[14];
    const float* wlb = (const float*)d_in[15];
    const float* gate_w = (const float*)d_in[16];
    const float* gate_b = (const float*)d_in[17];
    const float* gat_wsrc = (const float*)d_in[18];
    const float* gat_bias = (const float*)d_in[22];
    const float* out_w = (const float*)d_in[23];
    const float* out_b = (const float*)d_in[24];
    const int* edge_index = (const int*)d_in[25];
    const int* frag_edge_index = (const int*)d_in[26];
    const int* cluster_index = (const int*)d_in[27];

    char* p = (char*)d_ws;
    auto alloc = [&](size_t bytes) { char* r = p; p += (bytes + 255) & ~(size_t)255; return (void*)r; };
    float* hA    = (float*)alloc((size_t)N * 128 * 4);     // fp32 node state (in-place updates)
    short* ea1   = (short*)alloc((size_t)E * 128 * 2);     // bf16
    float* xp    = (float*)alloc((size_t)N * 128 * 4);     // fp32
    short* ep    = (short*)alloc((size_t)E * 128 * 2);     // bf16
    short* Y     = (short*)alloc((size_t)N * 1024 * 2);    // bf16 (aliased later)
    float* agg   = (float*)alloc((size_t)N * 128 * 4);     // fp32
    short* la_wTh = (short*)alloc(128 * 128 * 2);
    short* la_wTl = (short*)alloc(128 * 128 * 2);
    short* lb_wTh = (short*)alloc(128 * 16 * 2);
    short* lb_wTl = (short*)alloc(128 * 16 * 2);
    short* wnTh   = (short*)alloc(3 * 128 * 128 * 2);
    short* wnTl   = (short*)alloc(3 * 128 * 128 * 2);
    short* wbH    = (short*)alloc(3 * 1024 * 128 * 2);
    short* gateTh = (short*)alloc(128 * 384 * 2);
    short* gateTl = (short*)alloc(128 * 384 * 2);
    float* wmF    = (float*)alloc(128 * 128 * 4);
    short* wmTh   = (short*)alloc(128 * 128 * 2);
    short* wmTl   = (short*)alloc(128 * 128 * 2);
    float* stats  = (float*)alloc(256 * 4);
    // alias tail-phase buffers into Y's region (Y dead by then)
    char* yq = (char*)Y;
    float* fpool = (float*)yq;              yq += (size_t)F * 128 * 4;
    float* fmv   = (float*)yq;              yq += (size_t)F * 128 * 4;
    int*   perm  = (int*)yq;

    auto cdiv = [](int a, int b) { return (a + b - 1) / b; };

    // ---- weight prep ----
    transpose_split<<<cdiv(128 * 128, 256), 256, 0, stream>>>(la_w, la_wTh, la_wTl, 128, 128);
    transpose_split<<<cdiv(16 * 128, 256), 256, 0, stream>>>(lb_w, lb_wTh, lb_wTl, 16, 128);
    for (int l = 0; l < 3; ++l)
        transpose_split<<<cdiv(128 * 128, 256), 256, 0, stream>>>(
            wn + (size_t)l * 16384, wnTh + (size_t)l * 16384, wnTl + (size_t)l * 16384, 128, 128);
    cvt_f2b<<<cdiv(3 * 1024 * 128, 256), 256, 0, stream>>>(wb, wbH, 3 * 1024 * 128);
    transpose_split<<<cdiv(384 * 128, 256), 256, 0, stream>>>(gate_w, gateTh, gateTl, 384, 128);
    build_wm<<<cdiv(128 * 128, 256), 256, 0, stream>>>(gat_wsrc, wmF);
    transpose_split<<<cdiv(128 * 128, 256), 256, 0, stream>>>(wmF, wmTh, wmTl, 128, 128);

    auto run_layer = [&](float* h, const short* ea_buf, const int* ei, int Mn, int Me, int layer) {
        const short* wnTh_l = wnTh + (size_t)layer * 16384;
        const short* wnTl_l = wnTl + (size_t)layer * 16384;
        const short* wb_l   = wbH + (size_t)layer * 131072;
        const float* wl_l   = wl + (size_t)layer * 384 * 8;
        const float* wlb_l  = wlb + (size_t)layer * 8;
        gemm_split<3, 0, 0><<<dim3(1, cdiv(Mn, 128)), 256, 0, stream>>>(h, wnTh_l, wnTl_l, nullptr, xp, Mn, 128, 128);
        gemm_bf16<0, 1><<<dim3(1, cdiv(Me, 128)), 256, 0, stream>>>(ea_buf, wnTh_l, nullptr, ep, Me, 128, 128);
        gemm_split<2, 0, 1><<<dim3(8, cdiv(Mn, 128)), 256, 0, stream>>>(xp, wb_l, nullptr, nullptr, Y, Mn, 1024, 128);
        hipMemsetAsync(agg, 0, (size_t)Mn * 128 * 4, stream);
        edge_fused<<<cdiv(Me, 4), 256, 0, stream>>>(xp, ep, Y, ei, wl_l, wlb_l, agg, Me);
        gate_gemm_split<<<dim3(1, cdiv(Mn, 128)), 256, 0, stream>>>(h, agg, gateTh, gateTl, gate_b, Mn);
    };

    // ---- atom path ----
    gemm_split<3, 0, 0><<<dim3(1, cdiv(N, 128)), 256, 0, stream>>>(x, la_wTh, la_wTl, la_b, hA, N, 128, 128);
    hipMemsetAsync(stats, 0, 1024, stream);
    bn_stats<<<256, 256, 0, stream>>>(hA, stats, stats + 128, N);
    bn_apply<<<2048, 256, 0, stream>>>(hA, stats, stats + 128, bn1_g, bn1_b, N);

    gemm_split<3, 0, 1><<<dim3(1, cdiv(E, 128)), 256, 0, stream>>>(edge_attr, lb_wTh, lb_wTl, lb_b, ea1, E, 128, 16);
    hipMemsetAsync(stats, 0, 1024, stream);
    bn_stats_bf<<<256, 256, 0, stream>>>(ea1, stats, stats + 128, E);
    bn_apply_bf<<<2048, 256, 0, stream>>>(ea1, stats, stats + 128, bn2_g, bn2_b, E);

    for (int l = 0; l < 3; ++l) run_layer(hA, ea1, edge_index, N, E, l);
    out_phase1<<<cdiv(N, 4), 256, 0, stream>>>(hA, out_w, out_b, gat_bias, (float*)d_out, N);

    // ---- fragment path ----
    gemm_split<3, 1, 0><<<dim3(1, cdiv(NF, 128)), 256, 0, stream>>>(frag_x, la_wTh, la_wTl, la_b, hA, NF, 128, 128);

    gemm_split<3, 0, 1><<<dim3(1, cdiv(EF, 128)), 256, 0, stream>>>(frag_ea, lb_wTh, lb_wTl, lb_b, ea1, EF, 128, 16);
    hipMemsetAsync(stats, 0, 1024, stream);
    bn_stats_bf<<<256, 256, 0, stream>>>(ea1, stats, stats + 128, EF);
    bn_apply_bf<<<2048, 256, 0, stream>>>(ea1, stats, stats + 128, bn2_g, bn2_b, EF);

    for (int l = 0; l < 3; ++l) run_layer(hA, ea1, frag_edge_index, NF, EF, l);

    perm_build<<<cdiv(NF, 256), 256, 0, stream>>>(cluster_index, perm, NF);
    seg_pool<<<cdiv(F * 128, 256), 256, 0, stream>>>(hA, perm, fpool, F, NF);
    gemm_split<3, 1, 0><<<dim3(1, cdiv(F, 128)), 256, 0, stream>>>(fpool, wmTh, wmTl, gat_bias, fmv, F, 128, 128);
    out_phase2<<<cdiv(F, 4), 256, 0, stream>>>(fmv, perm, out_w, gat_bias, (float*)d_out, F);
}

// Round 5
// 1677.117 us; speedup vs baseline: 2.8923x; 1.0561x over previous
//
#include <hip/hip_runtime.h>
#include <hip/hip_bf16.h>

#define EPS 1e-5f

typedef short bf16x8 __attribute__((ext_vector_type(8)));
typedef short short4v __attribute__((ext_vector_type(4)));
typedef float f32x4 __attribute__((ext_vector_type(4)));

static __device__ __forceinline__ short f2bf(float x) {
    __hip_bfloat16 h = __float2bfloat16(x);
    return *reinterpret_cast<short*>(&h);
}
static __device__ __forceinline__ float bf2f(short x) {
    __hip_bfloat16 h;
    *reinterpret_cast<short*>(&h) = x;
    return __bfloat162float(h);
}

static __device__ __forceinline__ float wave_reduce(float v) {
    #pragma unroll
    for (int off = 32; off; off >>= 1) v += __shfl_xor(v, off);
    return v;
}

// ========== split-bf16 MFMA GEMM: C = act(A[M,K](f32) @ BT[N,K]^T + bias) ==========
// SPLIT=3: A hi/lo, B hi/lo. OUTM: 0=f32, 1=bf16, 2=bf16 hi/lo pair (Cout,Cout2)
template<int SPLIT, int ACT, int OUTM>
__global__ __launch_bounds__(256) void gemm_split(const float* __restrict__ A,
                                                  const short* __restrict__ BTh,
                                                  const short* __restrict__ BTl,
                                                  const float* __restrict__ bias,
                                                  void* __restrict__ Cout,
                                                  void* __restrict__ Cout2,
                                                  int M, int N, int K) {
    __shared__ short Ah[128][40];
    __shared__ short Al[128][40];
    __shared__ short Bh[128][40];
    __shared__ short Bl[128][40];
    const int tid = threadIdx.x;
    const int row0 = blockIdx.y * 128, col0 = blockIdx.x * 128;
    const int lane = tid & 63, w = tid >> 6;
    const int wr = w >> 1, wc = w & 1;
    const int lr = lane & 15, lg = lane >> 4;
    f32x4 acc[4][4] = {};

    for (int k0 = 0; k0 < K; k0 += 32) {
        #pragma unroll
        for (int i = 0; i < 4; ++i) {
            int idx = i * 256 + tid;
            int r = idx >> 3, q = idx & 7;
            int gr = row0 + r, gk = k0 + q * 4;
            f32x4 v;
            if (gr < M && gk + 3 < K) {
                v = *reinterpret_cast<const f32x4*>(&A[(size_t)gr * K + gk]);
            } else {
                #pragma unroll
                for (int j = 0; j < 4; ++j)
                    v[j] = (gr < M && gk + j < K) ? A[(size_t)gr * K + gk + j] : 0.f;
            }
            short4v h, l;
            #pragma unroll
            for (int j = 0; j < 4; ++j) {
                h[j] = f2bf(v[j]);
                l[j] = f2bf(v[j] - bf2f(h[j]));
            }
            *reinterpret_cast<short4v*>(&Ah[r][q * 4]) = h;
            *reinterpret_cast<short4v*>(&Al[r][q * 4]) = l;
        }
        #pragma unroll
        for (int i = 0; i < 4; ++i) {
            int idx = i * 256 + tid;
            int r = idx >> 3, q = idx & 7;
            int gc = col0 + r, gk = k0 + q * 4;
            short4v u, ul;
            if (gk + 3 < K) {
                u = *reinterpret_cast<const short4v*>(&BTh[(size_t)gc * K + gk]);
                if (SPLIT == 3) ul = *reinterpret_cast<const short4v*>(&BTl[(size_t)gc * K + gk]);
            } else {
                #pragma unroll
                for (int j = 0; j < 4; ++j) {
                    u[j] = (gk + j < K) ? BTh[(size_t)gc * K + gk + j] : (short)0;
                    if (SPLIT == 3) ul[j] = (gk + j < K) ? BTl[(size_t)gc * K + gk + j] : (short)0;
                }
            }
            *reinterpret_cast<short4v*>(&Bh[r][q * 4]) = u;
            if (SPLIT == 3) *reinterpret_cast<short4v*>(&Bl[r][q * 4]) = ul;
        }
        __syncthreads();
        bf16x8 afh[4], afl[4], bfh[4];
        #pragma unroll
        for (int mi = 0; mi < 4; ++mi) {
            afh[mi] = *reinterpret_cast<const bf16x8*>(&Ah[wr * 64 + mi * 16 + lr][lg * 8]);
            afl[mi] = *reinterpret_cast<const bf16x8*>(&Al[wr * 64 + mi * 16 + lr][lg * 8]);
        }
        #pragma unroll
        for (int ni = 0; ni < 4; ++ni)
            bfh[ni] = *reinterpret_cast<const bf16x8*>(&Bh[wc * 64 + ni * 16 + lr][lg * 8]);
        #pragma unroll
        for (int mi = 0; mi < 4; ++mi)
            #pragma unroll
            for (int ni = 0; ni < 4; ++ni) {
                acc[mi][ni] = __builtin_amdgcn_mfma_f32_16x16x32_bf16(afh[mi], bfh[ni], acc[mi][ni], 0, 0, 0);
                acc[mi][ni] = __builtin_amdgcn_mfma_f32_16x16x32_bf16(afl[mi], bfh[ni], acc[mi][ni], 0, 0, 0);
            }
        if (SPLIT == 3) {
            bf16x8 bfl[4];
            #pragma unroll
            for (int ni = 0; ni < 4; ++ni)
                bfl[ni] = *reinterpret_cast<const bf16x8*>(&Bl[wc * 64 + ni * 16 + lr][lg * 8]);
            #pragma unroll
            for (int mi = 0; mi < 4; ++mi)
                #pragma unroll
                for (int ni = 0; ni < 4; ++ni)
                    acc[mi][ni] = __builtin_amdgcn_mfma_f32_16x16x32_bf16(afh[mi], bfl[ni], acc[mi][ni], 0, 0, 0);
        }
        __syncthreads();
    }

    #pragma unroll
    for (int mi = 0; mi < 4; ++mi) {
        #pragma unroll
        for (int ni = 0; ni < 4; ++ni) {
            int col = col0 + wc * 64 + ni * 16 + lr;
            float bv = bias ? bias[col] : 0.f;
            #pragma unroll
            for (int r = 0; r < 4; ++r) {
                int row = row0 + wr * 64 + mi * 16 + lg * 4 + r;
                if (row >= M) continue;
                float v = acc[mi][ni][r] + bv;
                if (ACT) v = fmaxf(v, 0.f);
                if (OUTM == 0) ((float*)Cout)[(size_t)row * N + col] = v;
                else if (OUTM == 1) ((short*)Cout)[(size_t)row * N + col] = f2bf(v);
                else {
                    short h = f2bf(v);
                    ((short*)Cout)[(size_t)row * N + col] = h;
                    ((short*)Cout2)[(size_t)row * N + col] = f2bf(v - bf2f(h));
                }
            }
        }
    }
}

// ========== plain bf16 GEMM (tolerant path: ep projection) ==========
template<int ACT, int OUTBF>
__global__ __launch_bounds__(256) void gemm_bf16(const short* __restrict__ A,
                                                 const short* __restrict__ BT,
                                                 const float* __restrict__ bias,
                                                 void* __restrict__ Cout,
                                                 int M, int N, int K) {
    __shared__ short As[128][40];
    __shared__ short Bs[128][40];
    const int tid = threadIdx.x;
    const int row0 = blockIdx.y * 128, col0 = blockIdx.x * 128;
    const int lane = tid & 63, w = tid >> 6;
    const int wr = w >> 1, wc = w & 1;
    const int lr = lane & 15, lg = lane >> 4;
    f32x4 acc[4][4] = {};

    for (int k0 = 0; k0 < K; k0 += 32) {
        #pragma unroll
        for (int i = 0; i < 4; ++i) {
            int idx = i * 256 + tid;
            int r = idx >> 3, q = idx & 7;
            int gk = k0 + q * 4;
            int gr = row0 + r;
            short4v v;
            if (gr < M && gk + 3 < K) {
                v = *reinterpret_cast<const short4v*>(&A[(size_t)gr * K + gk]);
            } else {
                #pragma unroll
                for (int j = 0; j < 4; ++j)
                    v[j] = (gr < M && gk + j < K) ? A[(size_t)gr * K + gk + j] : (short)0;
            }
            *reinterpret_cast<short4v*>(&As[r][q * 4]) = v;
            int gc = col0 + r;
            short4v u;
            if (gc < N && gk + 3 < K) {
                u = *reinterpret_cast<const short4v*>(&BT[(size_t)gc * K + gk]);
            } else {
                #pragma unroll
                for (int j = 0; j < 4; ++j)
                    u[j] = (gc < N && gk + j < K) ? BT[(size_t)gc * K + gk + j] : (short)0;
            }
            *reinterpret_cast<short4v*>(&Bs[r][q * 4]) = u;
        }
        __syncthreads();
        bf16x8 af[4], bfr[4];
        #pragma unroll
        for (int mi = 0; mi < 4; ++mi)
            af[mi] = *reinterpret_cast<const bf16x8*>(&As[wr * 64 + mi * 16 + lr][lg * 8]);
        #pragma unroll
        for (int ni = 0; ni < 4; ++ni)
            bfr[ni] = *reinterpret_cast<const bf16x8*>(&Bs[wc * 64 + ni * 16 + lr][lg * 8]);
        #pragma unroll
        for (int mi = 0; mi < 4; ++mi)
            #pragma unroll
            for (int ni = 0; ni < 4; ++ni)
                acc[mi][ni] = __builtin_amdgcn_mfma_f32_16x16x32_bf16(af[mi], bfr[ni], acc[mi][ni], 0, 0, 0);
        __syncthreads();
    }

    #pragma unroll
    for (int mi = 0; mi < 4; ++mi) {
        #pragma unroll
        for (int ni = 0; ni < 4; ++ni) {
            int col = col0 + wc * 64 + ni * 16 + lr;
            float bv = bias ? bias[col] : 0.f;
            #pragma unroll
            for (int r = 0; r < 4; ++r) {
                int row = row0 + wr * 64 + mi * 16 + lg * 4 + r;
                if (row >= M) continue;
                float v = acc[mi][ni][r] + bv;
                if (ACT) v = fmaxf(v, 0.f);
                if (OUTBF) ((short*)Cout)[(size_t)row * N + col] = f2bf(v);
                else       ((float*)Cout)[(size_t)row * N + col] = v;
            }
        }
    }
}

// ========== Y GEMM: Y[M,1024] = (xph+xpl)[M,128] @ wbH[1024,128]^T ==========
// A staged in LDS once (hi/lo, full K=128); B fragments read directly from global (L2-resident).
// One barrier per block; column-tile loop.
__global__ __launch_bounds__(256) void gemm_y(const short* __restrict__ xph,
                                              const short* __restrict__ xpl,
                                              const short* __restrict__ BT,
                                              short* __restrict__ Y, int M) {
    __shared__ short Ah[128][136];
    __shared__ short Al[128][136];
    const int tid = threadIdx.x;
    const int row0 = blockIdx.x * 128;
    const int lane = tid & 63, w = tid >> 6;
    const int wr = w >> 1, wc = w & 1;
    const int lr = lane & 15, lg = lane >> 4;

    // stage full A (128 rows x 128 cols, hi+lo): 128*16 chunks of 8 = 2048 chunks
    #pragma unroll
    for (int i = 0; i < 8; ++i) {
        int idx = i * 256 + tid;
        int r = idx >> 4, q = idx & 15;
        int gr = row0 + r;
        bf16x8 vh, vl;
        if (gr < M) {
            vh = *reinterpret_cast<const bf16x8*>(&xph[(size_t)gr * 128 + q * 8]);
            vl = *reinterpret_cast<const bf16x8*>(&xpl[(size_t)gr * 128 + q * 8]);
        } else {
            #pragma unroll
            for (int j = 0; j < 8; ++j) { vh[j] = 0; vl[j] = 0; }
        }
        *reinterpret_cast<bf16x8*>(&Ah[r][q * 8]) = vh;
        *reinterpret_cast<bf16x8*>(&Al[r][q * 8]) = vl;
    }
    __syncthreads();

    for (int ct = 0; ct < 8; ++ct) {
        f32x4 acc[4][4] = {};
        #pragma unroll
        for (int k = 0; k < 4; ++k) {
            bf16x8 bfr[4];
            #pragma unroll
            for (int ni = 0; ni < 4; ++ni) {
                int col = ct * 128 + wc * 64 + ni * 16 + lr;
                bfr[ni] = *reinterpret_cast<const bf16x8*>(&BT[(size_t)col * 128 + k * 32 + lg * 8]);
            }
            bf16x8 ah[4], al[4];
            #pragma unroll
            for (int mi = 0; mi < 4; ++mi) {
                ah[mi] = *reinterpret_cast<const bf16x8*>(&Ah[wr * 64 + mi * 16 + lr][k * 32 + lg * 8]);
                al[mi] = *reinterpret_cast<const bf16x8*>(&Al[wr * 64 + mi * 16 + lr][k * 32 + lg * 8]);
            }
            #pragma unroll
            for (int mi = 0; mi < 4; ++mi)
                #pragma unroll
                for (int ni = 0; ni < 4; ++ni) {
                    acc[mi][ni] = __builtin_amdgcn_mfma_f32_16x16x32_bf16(ah[mi], bfr[ni], acc[mi][ni], 0, 0, 0);
                    acc[mi][ni] = __builtin_amdgcn_mfma_f32_16x16x32_bf16(al[mi], bfr[ni], acc[mi][ni], 0, 0, 0);
                }
        }
        #pragma unroll
        for (int mi = 0; mi < 4; ++mi) {
            #pragma unroll
            for (int ni = 0; ni < 4; ++ni) {
                int col = ct * 128 + wc * 64 + ni * 16 + lr;
                #pragma unroll
                for (int r = 0; r < 4; ++r) {
                    int row = row0 + wr * 64 + mi * 16 + lg * 4 + r;
                    if (row >= M) continue;
                    Y[(size_t)row * 1024 + col] = f2bf(acc[mi][ni][r]);
                }
            }
        }
    }
}

// ========== gate GEMM (split-3, in place) ==========
__global__ __launch_bounds__(256) void gate_gemm_split(float* __restrict__ h,
                                                       const float* __restrict__ aggv,
                                                       const short* __restrict__ BTh,
                                                       const short* __restrict__ BTl,
                                                       const float* __restrict__ gb,
                                                       int M) {
    __shared__ short Ah[128][40];
    __shared__ short Al[128][40];
    __shared__ short Bh[128][40];
    __shared__ short Bl[128][40];
    const int tid = threadIdx.x;
    const int row0 = blockIdx.y * 128;
    const int lane = tid & 63, w = tid >> 6;
    const int wr = w >> 1, wc = w & 1;
    const int lr = lane & 15, lg = lane >> 4;
    f32x4 acc[4][4] = {};

    for (int k0 = 0; k0 < 384; k0 += 32) {
        int sec = k0 >> 7;
        #pragma unroll
        for (int i = 0; i < 4; ++i) {
            int idx = i * 256 + tid;
            int r = idx >> 3, q = idx & 7;
            int gr = row0 + r;
            int ks = (k0 & 127) + q * 4;
            f32x4 v;
            if (gr < M) {
                if (sec == 0) {
                    v = *reinterpret_cast<const f32x4*>(&h[(size_t)gr * 128 + ks]);
                } else if (sec == 1) {
                    f32x4 a = *reinterpret_cast<const f32x4*>(&aggv[(size_t)gr * 128 + ks]);
                    #pragma unroll
                    for (int j = 0; j < 4; ++j) v[j] = fmaxf(a[j], 0.f);
                } else {
                    f32x4 hv = *reinterpret_cast<const f32x4*>(&h[(size_t)gr * 128 + ks]);
                    f32x4 a = *reinterpret_cast<const f32x4*>(&aggv[(size_t)gr * 128 + ks]);
                    #pragma unroll
                    for (int j = 0; j < 4; ++j) v[j] = hv[j] - fmaxf(a[j], 0.f);
                }
            } else {
                #pragma unroll
                for (int j = 0; j < 4; ++j) v[j] = 0.f;
            }
            short4v hh, ll;
            #pragma unroll
            for (int j = 0; j < 4; ++j) {
                hh[j] = f2bf(v[j]);
                ll[j] = f2bf(v[j] - bf2f(hh[j]));
            }
            *reinterpret_cast<short4v*>(&Ah[r][q * 4]) = hh;
            *reinterpret_cast<short4v*>(&Al[r][q * 4]) = ll;
        }
        #pragma unroll
        for (int i = 0; i < 4; ++i) {
            int idx = i * 256 + tid;
            int r = idx >> 3, q = idx & 7;
            short4v u  = *reinterpret_cast<const short4v*>(&BTh[(size_t)r * 384 + k0 + q * 4]);
            short4v ul = *reinterpret_cast<const short4v*>(&BTl[(size_t)r * 384 + k0 + q * 4]);
            *reinterpret_cast<short4v*>(&Bh[r][q * 4]) = u;
            *reinterpret_cast<short4v*>(&Bl[r][q * 4]) = ul;
        }
        __syncthreads();
        bf16x8 afh[4], afl[4], bfh[4], bfl[4];
        #pragma unroll
        for (int mi = 0; mi < 4; ++mi) {
            afh[mi] = *reinterpret_cast<const bf16x8*>(&Ah[wr * 64 + mi * 16 + lr][lg * 8]);
            afl[mi] = *reinterpret_cast<const bf16x8*>(&Al[wr * 64 + mi * 16 + lr][lg * 8]);
        }
        #pragma unroll
        for (int ni = 0; ni < 4; ++ni) {
            bfh[ni] = *reinterpret_cast<const bf16x8*>(&Bh[wc * 64 + ni * 16 + lr][lg * 8]);
            bfl[ni] = *reinterpret_cast<const bf16x8*>(&Bl[wc * 64 + ni * 16 + lr][lg * 8]);
        }
        #pragma unroll
        for (int mi = 0; mi < 4; ++mi)
            #pragma unroll
            for (int ni = 0; ni < 4; ++ni) {
                acc[mi][ni] = __builtin_amdgcn_mfma_f32_16x16x32_bf16(afh[mi], bfh[ni], acc[mi][ni], 0, 0, 0);
                acc[mi][ni] = __builtin_amdgcn_mfma_f32_16x16x32_bf16(afl[mi], bfh[ni], acc[mi][ni], 0, 0, 0);
                acc[mi][ni] = __builtin_amdgcn_mfma_f32_16x16x32_bf16(afh[mi], bfl[ni], acc[mi][ni], 0, 0, 0);
            }
        __syncthreads();
    }

    #pragma unroll
    for (int mi = 0; mi < 4; ++mi) {
        #pragma unroll
        for (int ni = 0; ni < 4; ++ni) {
            int col = wc * 64 + ni * 16 + lr;
            float gbv = gb[col];
            #pragma unroll
            for (int r = 0; r < 4; ++r) {
                int row = row0 + wr * 64 + mi * 16 + lg * 4 + r;
                if (row >= M) continue;
                float beta = fmaxf(acc[mi][ni][r] + gbv, 0.f);
                float hv = h[(size_t)row * 128 + col];
                float hh = fmaxf(aggv[(size_t)row * 128 + col], 0.f);
                h[(size_t)row * 128 + col] = beta * hv + (1.f - beta) * hh;
            }
        }
    }
}

// ========== fused edge kernel ==========
__global__ __launch_bounds__(256) void edge_fused(const short* __restrict__ xph,
                                                  const short* __restrict__ xpl,
                                                  const short* __restrict__ ep,
                                                  const short* __restrict__ Y,
                                                  const int* __restrict__ ei,
                                                  const float* __restrict__ wl,
                                                  const float* __restrict__ wlb,
                                                  float* __restrict__ agg, int E) {
    __shared__ float swl[384][9];
    __shared__ float swlb[8];
    for (int i = threadIdx.x; i < 384 * 8; i += 256) swl[i >> 3][i & 7] = wl[i];
    if (threadIdx.x < 8) swlb[threadIdx.x] = wlb[threadIdx.x];
    __syncthreads();
    int e = blockIdx.x * 4 + (threadIdx.x >> 6);
    if (e >= E) return;
    int l = threadIdx.x & 63;
    int src = ei[e], dst = ei[E + e];
    const short* xSh = xph + (size_t)src * 128;
    const short* xSl = xpl + (size_t)src * 128;
    const short* xDh = xph + (size_t)dst * 128;
    const short* xDl = xpl + (size_t)dst * 128;
    const short* er = ep + (size_t)e * 128;
    const short* y  = Y + (size_t)src * 1024;
    float xi0 = bf2f(xDh[l]) + bf2f(xDl[l]);
    float xi1 = bf2f(xDh[l + 64]) + bf2f(xDl[l + 64]);
    float xj0 = bf2f(xSh[l]) + bf2f(xSl[l]);
    float xj1 = bf2f(xSh[l + 64]) + bf2f(xSl[l + 64]);
    float e0 = bf2f(er[l]), e1 = bf2f(er[l + 64]);
    float t[8];
    #pragma unroll
    for (int s = 0; s < 8; ++s) {
        float p = xi0 * (bf2f(y[s * 128 + l]) + swl[l][s])
                + xi1 * (bf2f(y[s * 128 + l + 64]) + swl[l + 64][s])
                + e0 * swl[128 + l][s] + e1 * swl[128 + l + 64][s]
                + xj0 * swl[256 + l][s] + xj1 * swl[256 + l + 64][s];
        t[s] = wave_reduce(p);
    }
    int g0 = l >> 4;
    float tg0 = (g0 == 0 ? t[0] : g0 == 1 ? t[1] : g0 == 2 ? t[2] : t[3]) + swlb[g0];
    float tg1 = (g0 == 0 ? t[4] : g0 == 1 ? t[5] : g0 == 2 ? t[6] : t[7]) + swlb[g0 + 4];
    float a0 = tanhf(tg0), a1 = tanhf(tg1);
    atomicAdd(&agg[(size_t)dst * 128 + l],      fmaxf(xj0, e0) * a0);
    atomicAdd(&agg[(size_t)dst * 128 + l + 64], fmaxf(xj1, e1) * a1);
}

// ========== batch norm (fp32 / bf16) ==========
__global__ void bn_stats(const float* __restrict__ z, float* __restrict__ gsum,
                         float* __restrict__ gsq, int M) {
    int c = threadIdx.x & 127;
    int rr = threadIdx.x >> 7;
    float s = 0.f, q = 0.f;
    for (int r = blockIdx.x * 2 + rr; r < M; r += gridDim.x * 2) {
        float v = z[(size_t)r * 128 + c];
        s += v; q += v * v;
    }
    __shared__ float ls[256], lq[256];
    ls[threadIdx.x] = s; lq[threadIdx.x] = q;
    __syncthreads();
    if (threadIdx.x < 128) {
        atomicAdd(&gsum[c], ls[threadIdx.x] + ls[threadIdx.x + 128]);
        atomicAdd(&gsq[c],  lq[threadIdx.x] + lq[threadIdx.x + 128]);
    }
}

__global__ void bn_apply(float* __restrict__ z, const float* __restrict__ gsum,
                         const float* __restrict__ gsq, const float* __restrict__ g,
                         const float* __restrict__ b, int M) {
    size_t total = (size_t)M * 128;
    for (size_t idx = (size_t)blockIdx.x * 256 + threadIdx.x; idx < total;
         idx += (size_t)gridDim.x * 256) {
        int c = idx & 127;
        float mu = gsum[c] / (float)M;
        float var = gsq[c] / (float)M - mu * mu;
        float rs = rsqrtf(var + EPS);
        float v = (z[idx] - mu) * rs * g[c] + b[c];
        z[idx] = fmaxf(v, 0.f);
    }
}

__global__ void bn_stats_bf(const short* __restrict__ z, float* __restrict__ gsum,
                            float* __restrict__ gsq, int M) {
    int c = threadIdx.x & 127;
    int rr = threadIdx.x >> 7;
    float s = 0.f, q = 0.f;
    for (int r = blockIdx.x * 2 + rr; r < M; r += gridDim.x * 2) {
        float v = bf2f(z[(size_t)r * 128 + c]);
        s += v; q += v * v;
    }
    __shared__ float ls[256], lq[256];
    ls[threadIdx.x] = s; lq[threadIdx.x] = q;
    __syncthreads();
    if (threadIdx.x < 128) {
        atomicAdd(&gsum[c], ls[threadIdx.x] + ls[threadIdx.x + 128]);
        atomicAdd(&gsq[c],  lq[threadIdx.x] + lq[threadIdx.x + 128]);
    }
}

__global__ void bn_apply_bf(short* __restrict__ z, const float* __restrict__ gsum,
                            const float* __restrict__ gsq, const float* __restrict__ g,
                            const float* __restrict__ b, int M) {
    size_t total = (size_t)M * 128;
    for (size_t idx = (size_t)blockIdx.x * 256 + threadIdx.x; idx < total;
         idx += (size_t)gridDim.x * 256) {
        int c = idx & 127;
        float mu = gsum[c] / (float)M;
        float var = gsq[c] / (float)M - mu * mu;
        float rs = rsqrtf(var + EPS);
        float v = (bf2f(z[idx]) - mu) * rs * g[c] + b[c];
        z[idx] = f2bf(fmaxf(v, 0.f));
    }
}

// ========== prep ==========
__global__ void transpose_split(const float* __restrict__ in, short* __restrict__ outh,
                                short* __restrict__ outl, int K, int N) {
    int idx = blockIdx.x * 256 + threadIdx.x;
    if (idx >= K * N) return;
    int nI = idx / K, k = idx - nI * K;
    float v = in[(size_t)k * N + nI];
    short h = f2bf(v);
    outh[idx] = h;
    outl[idx] = f2bf(v - bf2f(h));
}

__global__ void cvt_f2b(const float* __restrict__ in, short* __restrict__ out, int n) {
    int i = blockIdx.x * 256 + threadIdx.x;
    if (i < n) out[i] = f2bf(in[i]);
}

__global__ void build_wm(const float* __restrict__ wsrc, float* __restrict__ wm) {
    int idx = blockIdx.x * 256 + threadIdx.x;
    if (idx >= 128 * 128) return;
    int d = idx >> 7, c = idx & 127;
    float s = 0.f;
    #pragma unroll
    for (int h = 0; h < 8; ++h) s += wsrc[(size_t)d * 1024 + h * 128 + c];
    wm[idx] = s * 0.125f;
}

__global__ void perm_build(const int* __restrict__ ci, int* __restrict__ perm, int NF) {
    int i = blockIdx.x * 256 + threadIdx.x;
    if (i >= NF) return;
    int c = ci[i];
    if (i == 0 || ci[i - 1] != c) perm[c] = i;
}

__global__ void seg_pool(const float* __restrict__ fx, const int* __restrict__ perm,
                         float* __restrict__ pool, int F, int NF) {
    int idx = blockIdx.x * 256 + threadIdx.x;
    if (idx >= F * 128) return;
    int f = idx >> 7, c = idx & 127;
    int s = perm[f];
    int e = (f + 1 < F) ? perm[f + 1] : NF;
    float acc = 0.f;
    for (int i = s; i < e; ++i) acc += fx[(size_t)i * 128 + c];
    pool[idx] = fmaxf(acc, 0.f);
}

// ========== output ==========
__global__ __launch_bounds__(256) void out_phase1(const float* __restrict__ h,
                                                  const float* __restrict__ out_w,
                                                  const float* __restrict__ out_b,
                                                  const float* __restrict__ gat_bias,
                                                  float* __restrict__ out, int M) {
    int n = blockIdx.x * 4 + (threadIdx.x >> 6);
    if (n >= M) return;
    int l = threadIdx.x & 63;
    float p = fmaxf(h[(size_t)n * 128 + l], 0.f) * out_w[l]
            + fmaxf(h[(size_t)n * 128 + l + 64], 0.f) * out_w[l + 64];
    p += fmaxf(gat_bias[l], 0.f) * out_w[128 + l]
       + fmaxf(gat_bias[l + 64], 0.f) * out_w[128 + l + 64];
    p = wave_reduce(p);
    if (l == 0) out[n] = p + out_b[0];
}

__global__ __launch_bounds__(256) void out_phase2(const float* __restrict__ fmv,
                                                  const int* __restrict__ perm,
                                                  const float* __restrict__ out_w,
                                                  const float* __restrict__ gat_bias,
                                                  float* __restrict__ out, int F) {
    int f = blockIdx.x * 4 + (threadIdx.x >> 6);
    if (f >= F) return;
    int l = threadIdx.x & 63;
    float p = fmv[(size_t)f * 128 + l] * out_w[128 + l]
            + fmv[(size_t)f * 128 + l + 64] * out_w[128 + l + 64];
    float b = fmaxf(gat_bias[l], 0.f) * out_w[128 + l]
            + fmaxf(gat_bias[l + 64], 0.f) * out_w[128 + l + 64];
    float d = wave_reduce(p - b);
    if (l == 0) out[perm[f]] += d;
}

// ========== host ==========
extern "C" void kernel_launch(void* const* d_in, const int* in_sizes, int n_in,
                              void* d_out, int out_size, void* d_ws, size_t ws_size,
                              hipStream_t stream) {
    const int N = 50000, E = 100000, NF = 20000, EF = 40000, F = 10000;

    const float* x          = (const float*)d_in[0];
    const float* edge_attr  = (const float*)d_in[1];
    const float* frag_x     = (const float*)d_in[2];
    const float* frag_ea    = (const float*)d_in[3];
    const float* la_w = (const float*)d_in[4];
    const float* la_b = (const float*)d_in[5];
    const float* lb_w = (const float*)d_in[6];
    const float* lb_b = (const float*)d_in[7];
    const float* bn1_g = (const float*)d_in[8];
    const float* bn1_b = (const float*)d_in[9];
    const float* bn2_g = (const float*)d_in[10];
    const float* bn2_b = (const float*)d_in[11];
    const float* wn = (const float*)d_in[12];
    const float* wb = (const float*)d_in[13];
    const float* wl = (const float*)d_in[14];
    const float* wlb = (const float*)d_in[15];
    const float* gate_w = (const float*)d_in[16];
    const float* gate_b = (const float*)d_in[17];
    const float* gat_wsrc = (const float*)d_in[18];
    const float* gat_bias = (const float*)d_in[22];
    const float* out_w = (const float*)d_in[23];
    const float* out_b = (const float*)d_in[24];
    const int* edge_index = (const int*)d_in[25];
    const int* frag_edge_index = (const int*)d_in[26];
    const int* cluster_index = (const int*)d_in[27];

    char* p = (char*)d_ws;
    auto alloc = [&](size_t bytes) { char* r = p; p += (bytes + 255) & ~(size_t)255; return (void*)r; };
    float* hA    = (float*)alloc((size_t)N * 128 * 4);
    short* ea1   = (short*)alloc((size_t)E * 128 * 2);
    short* xph   = (short*)alloc((size_t)N * 128 * 2);
    short* xpl   = (short*)alloc((size_t)N * 128 * 2);
    short* ep    = (short*)alloc((size_t)E * 128 * 2);
    short* Y     = (short*)alloc((size_t)N * 1024 * 2);
    float* agg   = (float*)alloc((size_t)N * 128 * 4);
    short* la_wTh = (short*)alloc(128 * 128 * 2);
    short* la_wTl = (short*)alloc(128 * 128 * 2);
    short* lb_wTh = (short*)alloc(128 * 16 * 2);
    short* lb_wTl = (short*)alloc(128 * 16 * 2);
    short* wnTh   = (short*)alloc(3 * 128 * 128 * 2);
    short* wnTl   = (short*)alloc(3 * 128 * 128 * 2);
    short* wbH    = (short*)alloc(3 * 1024 * 128 * 2);
    short* gateTh = (short*)alloc(128 * 384 * 2);
    short* gateTl = (short*)alloc(128 * 384 * 2);
    float* wmF    = (float*)alloc(128 * 128 * 4);
    short* wmTh   = (short*)alloc(128 * 128 * 2);
    short* wmTl   = (short*)alloc(128 * 128 * 2);
    float* stats  = (float*)alloc(256 * 4);
    char* yq = (char*)Y;
    float* fpool = (float*)yq;              yq += (size_t)F * 128 * 4;
    float* fmv   = (float*)yq;              yq += (size_t)F * 128 * 4;
    int*   perm  = (int*)yq;

    auto cdiv = [](int a, int b) { return (a + b - 1) / b; };

    // ---- weight prep ----
    transpose_split<<<cdiv(128 * 128, 256), 256, 0, stream>>>(la_w, la_wTh, la_wTl, 128, 128);
    transpose_split<<<cdiv(16 * 128, 256), 256, 0, stream>>>(lb_w, lb_wTh, lb_wTl, 16, 128);
    for (int l = 0; l < 3; ++l)
        transpose_split<<<cdiv(128 * 128, 256), 256, 0, stream>>>(
            wn + (size_t)l * 16384, wnTh + (size_t)l * 16384, wnTl + (size_t)l * 16384, 128, 128);
    cvt_f2b<<<cdiv(3 * 1024 * 128, 256), 256, 0, stream>>>(wb, wbH, 3 * 1024 * 128);
    transpose_split<<<cdiv(384 * 128, 256), 256, 0, stream>>>(gate_w, gateTh, gateTl, 384, 128);
    build_wm<<<cdiv(128 * 128, 256), 256, 0, stream>>>(gat_wsrc, wmF);
    transpose_split<<<cdiv(128 * 128, 256), 256, 0, stream>>>(wmF, wmTh, wmTl, 128, 128);

    auto run_layer = [&](float* h, const short* ea_buf, const int* ei, int Mn, int Me, int layer) {
        const short* wnTh_l = wnTh + (size_t)layer * 16384;
        const short* wnTl_l = wnTl + (size_t)layer * 16384;
        const short* wb_l   = wbH + (size_t)layer * 131072;
        const float* wl_l   = wl + (size_t)layer * 384 * 8;
        const float* wlb_l  = wlb + (size_t)layer * 8;
        gemm_split<3, 0, 2><<<dim3(1, cdiv(Mn, 128)), 256, 0, stream>>>(h, wnTh_l, wnTl_l, nullptr, xph, xpl, Mn, 128, 128);
        gemm_bf16<0, 1><<<dim3(1, cdiv(Me, 128)), 256, 0, stream>>>(ea_buf, wnTh_l, nullptr, ep, Me, 128, 128);
        gemm_y<<<cdiv(Mn, 128), 256, 0, stream>>>(xph, xpl, wb_l, Y, Mn);
        hipMemsetAsync(agg, 0, (size_t)Mn * 128 * 4, stream);
        edge_fused<<<cdiv(Me, 4), 256, 0, stream>>>(xph, xpl, ep, Y, ei, wl_l, wlb_l, agg, Me);
        gate_gemm_split<<<dim3(1, cdiv(Mn, 128)), 256, 0, stream>>>(h, agg, gateTh, gateTl, gate_b, Mn);
    };

    // ---- atom path ----
    gemm_split<3, 0, 0><<<dim3(1, cdiv(N, 128)), 256, 0, stream>>>(x, la_wTh, la_wTl, la_b, hA, nullptr, N, 128, 128);
    hipMemsetAsync(stats, 0, 1024, stream);
    bn_stats<<<256, 256, 0, stream>>>(hA, stats, stats + 128, N);
    bn_apply<<<2048, 256, 0, stream>>>(hA, stats, stats + 128, bn1_g, bn1_b, N);

    gemm_split<3, 0, 1><<<dim3(1, cdiv(E, 128)), 256, 0, stream>>>(edge_attr, lb_wTh, lb_wTl, lb_b, ea1, nullptr, E, 128, 16);
    hipMemsetAsync(stats, 0, 1024, stream);
    bn_stats_bf<<<256, 256, 0, stream>>>(ea1, stats, stats + 128, E);
    bn_apply_bf<<<2048, 256, 0, stream>>>(ea1, stats, stats + 128, bn2_g, bn2_b, E);

    for (int l = 0; l < 3; ++l) run_layer(hA, ea1, edge_index, N, E, l);
    out_phase1<<<cdiv(N, 4), 256, 0, stream>>>(hA, out_w, out_b, gat_bias, (float*)d_out, N);

    // ---- fragment path ----
    gemm_split<3, 1, 0><<<dim3(1, cdiv(NF, 128)), 256, 0, stream>>>(frag_x, la_wTh, la_wTl, la_b, hA, nullptr, NF, 128, 128);

    gemm_split<3, 0, 1><<<dim3(1, cdiv(EF, 128)), 256, 0, stream>>>(frag_ea, lb_wTh, lb_wTl, lb_b, ea1, nullptr, EF, 128, 16);
    hipMemsetAsync(stats, 0, 1024, stream);
    bn_stats_bf<<<256, 256, 0, stream>>>(ea1, stats, stats + 128, EF);
    bn_apply_bf<<<2048, 256, 0, stream>>>(ea1, stats, stats + 128, bn2_g, bn2_b, EF);

    for (int l = 0; l < 3; ++l) run_layer(hA, ea1, frag_edge_index, NF, EF, l);

    perm_build<<<cdiv(NF, 256), 256, 0, stream>>>(cluster_index, perm, NF);
    seg_pool<<<cdiv(F * 128, 256), 256, 0, stream>>>(hA, perm, fpool, F, NF);
    gemm_split<3, 1, 0><<<dim3(1, cdiv(F, 128)), 256, 0, stream>>>(fpool, wmTh, wmTl, gat_bias, fmv, nullptr, F, 128, 128);
    out_phase2<<<cdiv(F, 4), 256, 0, stream>>>(fmv, perm, out_w, gat_bias, (float*)d_out, F);
}